// Round 7
// baseline (1910.725 us; speedup 1.0000x reference)
//
#include <hip/hip_runtime.h>

#define N_NODES 100000
#define N_EDGES 3200000
#define D 64
#define G_GRAPHS 64
#define L_LAYERS 5
#define BN_EPS 1e-5f
#define RPW 8

__device__ __forceinline__ unsigned short f2bf(float f) {  // RNE f32->bf16
    unsigned int u = __float_as_uint(f);
    u += 0x7FFFu + ((u >> 16) & 1u);
    return (unsigned short)(u >> 16);
}
__device__ __forceinline__ float bf2f(unsigned short v) {
    return __uint_as_float((unsigned int)v << 16);
}

// async global->LDS, 16B per lane; LDS dest is wave-uniform base + lane*16
__device__ __forceinline__ void gload_lds16(const void* g, void* l) {
    __builtin_amdgcn_global_load_lds(
        (const __attribute__((address_space(1))) unsigned int*)g,
        (__attribute__((address_space(3))) unsigned int*)l, 16, 0, 0);
}

// ---------------- x -> bf16 -------------------------------------------------
__global__ __launch_bounds__(256) void xcvt_kernel(const float* __restrict__ x,
                                                   ushort* __restrict__ xbf) {
    const float4* x4 = (const float4*)x;
    ushort4* o4 = (ushort4*)xbf;
    const int total = N_NODES * D / 4;
    for (int i = blockIdx.x * blockDim.x + threadIdx.x; i < total;
         i += gridDim.x * blockDim.x) {
        float4 v = x4[i];
        ushort4 o;
        o.x = f2bf(v.x); o.y = f2bf(v.y); o.z = f2bf(v.z); o.w = f2bf(v.w);
        o4[i] = o;
    }
}

// ---------------- dense CSR build (hist -> scan -> scatter) ------------------
__global__ __launch_bounds__(256) void hist_kernel(const int* __restrict__ ei,
                                                   int* __restrict__ deg) {
    const int4* d4 = (const int4*)(ei + N_EDGES);
    const int n4 = N_EDGES / 4;
    for (int i = blockIdx.x * blockDim.x + threadIdx.x; i < n4;
         i += gridDim.x * blockDim.x) {
        int4 v = d4[i];
        atomicAdd(&deg[v.x], 1);
        atomicAdd(&deg[v.y], 1);
        atomicAdd(&deg[v.z], 1);
        atomicAdd(&deg[v.w], 1);
    }
}

__global__ __launch_bounds__(1024) void scan_kernel(const int* __restrict__ deg,
                                                    int* __restrict__ row_ptr,
                                                    int* __restrict__ cursor) {
    __shared__ int part[1024];
    int t = threadIdx.x;
    const int CH = (N_NODES + 1023) / 1024;  // 98
    int s = t * CH;
    int e = min(s + CH, N_NODES);
    int sum = 0;
    for (int i = s; i < e; ++i) sum += deg[i];
    part[t] = sum;
    __syncthreads();
    for (int off = 1; off < 1024; off <<= 1) {
        int v = (t >= off) ? part[t - off] : 0;
        __syncthreads();
        part[t] += v;
        __syncthreads();
    }
    int base = part[t] - sum;
    for (int i = s; i < e; ++i) {
        row_ptr[i] = base;
        cursor[i]  = base;
        base += deg[i];
    }
    if (t == 1023) row_ptr[N_NODES] = N_EDGES;
}

// entry = (src << 15) | quant15(attr)
__device__ __forceinline__ unsigned enc_edge(int s, float a) {
    float q = fminf(fmaxf((a + 8.0f) * 2048.0f, 0.0f), 32767.0f);
    return ((unsigned)s << 15) | (unsigned)__float2int_rn(q);
}

__global__ __launch_bounds__(256) void scatter_kernel(const int* __restrict__ ei,
                                                      const float* __restrict__ ea,
                                                      int* __restrict__ cursor,
                                                      unsigned* __restrict__ perm) {
    const int4* s4 = (const int4*)ei;
    const int4* d4 = (const int4*)(ei + N_EDGES);
    const float4* a4 = (const float4*)ea;
    const int n4 = N_EDGES / 4;
    for (int i = blockIdx.x * blockDim.x + threadIdx.x; i < n4;
         i += gridDim.x * blockDim.x) {
        int4 sv = s4[i];
        int4 dv = d4[i];
        float4 av = a4[i];
        int p;
        p = atomicAdd(&cursor[dv.x], 1); perm[p] = enc_edge(sv.x, av.x);
        p = atomicAdd(&cursor[dv.y], 1); perm[p] = enc_edge(sv.y, av.y);
        p = atomicAdd(&cursor[dv.z], 1); perm[p] = enc_edge(sv.z, av.z);
        p = atomicAdd(&cursor[dv.w], 1); perm[p] = enc_edge(sv.w, av.w);
    }
}

// ---------------- fused GINE layer -----------------------------------------
// Per wave: rows r0..r0+7 (dense CSR). Chunk stream of 32-edge chunks staged
// into a 3-slot LDS ring via global_load_lds; counted vmcnt(8/4/0) keeps two
// chunks in flight while the oldest is accumulated and rows finalize (GEMMs).
__global__ __launch_bounds__(256, 2) void layer_kernel(
    const ushort* __restrict__ hbf,      // [N][D] bf16
    const int* __restrict__ row_ptr,
    const unsigned* __restrict__ perm,
    const float* __restrict__ eps, int layer,
    const float* __restrict__ edgeW, const float* __restrict__ edgeB,
    const float* __restrict__ W1, const float* __restrict__ b1,
    const float* __restrict__ bng, const float* __restrict__ bnb,
    const float* __restrict__ W2, const float* __restrict__ b2,
    const int* __restrict__ batch,
    ushort* __restrict__ hout,           // [N][D] bf16
    float* __restrict__ pooled /* [G][D] this layer */) {
    __shared__ ushort Wb1[D * D];                       // 8 KB
    __shared__ ushort Wb2[D * D];                       // 8 KB
    __shared__ float bl1s[D];
    __shared__ float bl2s[D];
    __shared__ __align__(16) ushort stage[4][3][2048];  // 4 waves x 3 bufs x 4KB
    __shared__ __align__(16) ushort selfst[4][512];     // 4 waves x 1KB self rows

    const float inv_std = rsqrtf(1.0f + BN_EPS);
    const int tid = threadIdx.x;
    for (int idx = tid; idx < D * D; idx += 256) {
        int j = idx & 63;
        Wb1[idx] = f2bf(W1[idx] * (bng[j] * inv_std));
        Wb2[idx] = f2bf(W2[idx]);
    }
    if (tid < D) {
        bl1s[tid] = fmaf(b1[tid], bng[tid] * inv_std, bnb[tid]);
        bl2s[tid] = b2[tid];
    }
    __syncthreads();

    const int lane = tid & 63;
    const int q = lane & 15;
    const int grp = lane >> 4;
    const int wid = tid >> 6;
    const int wv = blockIdx.x * 4 + wid;
    const int r0 = wv * RPW;          // N = 12500*8 exactly
    if (r0 >= N_NODES) return;

    int rpv = 0;
    if (lane < 9) rpv = row_ptr[r0 + lane];
    int cvl = __shfl(rpv, lane + 1) - rpv;     // degree, valid lane<8
    int bval = 0;
    if (lane < RPW) bval = batch[r0 + lane];

    const float ev = 1.0f + eps[layer];
    const float QDEC = 4.8828125e-4f;  // 1/2048
    float w4[4], b4[4], blv1[4], blv2[4];
    {
        float4 t = ((const float4*)edgeW)[q];
        w4[0] = t.x; w4[1] = t.y; w4[2] = t.z; w4[3] = t.w;
        float4 u = ((const float4*)edgeB)[q];
        b4[0] = u.x; b4[1] = u.y; b4[2] = u.z; b4[3] = u.w;
        float4 v = ((const float4*)bl1s)[q];
        blv1[0] = v.x; blv1[1] = v.y; blv1[2] = v.z; blv1[3] = v.w;
        float4 w = ((const float4*)bl2s)[q];
        blv2[0] = w.x; blv2[1] = w.y; blv2[2] = w.z; blv2[3] = w.w;
    }
    const ushort4* h4 = (const ushort4*)hbf;
    ushort4* o4 = (ushort4*)hout;
    ushort* selfb = &selfst[wid][0];

    // stage the 8 self rows (1 instr, oldest in vmcnt queue)
    {
        int row = lane >> 3, sub = lane & 7;
        gload_lds16(hbf + (size_t)(r0 + row) * D + sub * 8, selfb);
    }

    auto nch = [&](int i) { return (__shfl(cvl, i) + 31) >> 5; };
    int nTot = 0;
    #pragma unroll
    for (int i = 0; i < RPW; ++i) nTot += nch(i);

    int ii = 0, ci = 0;
    while (ii < RPW && nch(ii) == 0) ++ii;
    auto adv = [&]() {
        ++ci;
        while (ii < RPW && ci >= nch(ii)) { ++ii; ci = 0; }
    };
    auto load_pv = [&](int i, int c) -> unsigned {
        int base = __shfl(rpv, i);
        int rem = __shfl(cvl, i) - (c << 5);
        unsigned v = 0;
        if (lane < 32 && lane < rem)
            v = __builtin_nontemporal_load(perm + base + (c << 5) + lane);
        return v;
    };
    auto issue = [&](unsigned pv, ushort* sb) {
        int eloc = lane >> 3, sub = lane & 7;
        #pragma unroll
        for (int j = 0; j < 4; ++j) {
            unsigned pe = __shfl(pv, (j << 3) + eloc);
            gload_lds16(hbf + (size_t)(pe >> 15) * D + sub * 8, sb + j * 512);
        }
    };
    auto accumulate = [&](unsigned pv, const ushort* sb, int eb, int cr, float* agg) {
        #pragma unroll
        for (int k = 0; k < 8; ++k) {
            int eidx = (k << 2) | grp;
            unsigned pe = __shfl(pv, eidx);
            float m = (eb + eidx < cr) ? 1.0f : 0.0f;
            float a = fmaf((float)(pe & 0x7FFFu), QDEC, -8.0f);
            ushort4 hv = *(const ushort4*)(sb + (eidx << 6) + (q << 2));
            agg[0] = fmaf(m, fmaxf(fmaf(a, w4[0], b4[0]) + bf2f(hv.x), 0.f), agg[0]);
            agg[1] = fmaf(m, fmaxf(fmaf(a, w4[1], b4[1]) + bf2f(hv.y), 0.f), agg[1]);
            agg[2] = fmaf(m, fmaxf(fmaf(a, w4[2], b4[2]) + bf2f(hv.z), 0.f), agg[2]);
            agg[3] = fmaf(m, fmaxf(fmaf(a, w4[3], b4[3]) + bf2f(hv.w), 0.f), agg[3]);
        }
    };

    int cur_g = -1;
    float rm[4] = {0.f, 0.f, 0.f, 0.f};
    auto flush_pool = [&]() {
        if (cur_g >= 0 && grp == 0) {
            unsigned* p = (unsigned*)&pooled[cur_g * D + 4 * q];
            atomicMax(p + 0, __float_as_uint(rm[0]));
            atomicMax(p + 1, __float_as_uint(rm[1]));
            atomicMax(p + 2, __float_as_uint(rm[2]));
            atomicMax(p + 3, __float_as_uint(rm[3]));
        }
    };
    auto pool = [&](int bg, const float* y) {
        if (bg != cur_g) {
            flush_pool();
            cur_g = bg;
            rm[0] = y[0]; rm[1] = y[1]; rm[2] = y[2]; rm[3] = y[3];
        } else {
            rm[0] = fmaxf(rm[0], y[0]); rm[1] = fmaxf(rm[1], y[1]);
            rm[2] = fmaxf(rm[2], y[2]); rm[3] = fmaxf(rm[3], y[3]);
        }
    };

    bool havePend = false;
    int rowPend = 0;
    float zP[4];

    auto finish_row = [&](int r, float* aggr) {
        float zc[4];
        #pragma unroll
        for (int c = 0; c < 4; ++c) {
            float a = aggr[c];
            a += __shfl_xor(a, 16);
            a += __shfl_xor(a, 32);
            zc[c] = a;
        }
        ushort4 hv = *(const ushort4*)(selfb + (r << 6) + (q << 2));
        zc[0] = fmaf(ev, bf2f(hv.x), zc[0]);
        zc[1] = fmaf(ev, bf2f(hv.y), zc[1]);
        zc[2] = fmaf(ev, bf2f(hv.z), zc[2]);
        zc[3] = fmaf(ev, bf2f(hv.w), zc[3]);
        if (!havePend) {
            zP[0] = zc[0]; zP[1] = zc[1]; zP[2] = zc[2]; zP[3] = zc[3];
            rowPend = r;
            havePend = true;
            return;
        }
        havePend = false;
        // ---- GEMM pair on rows (rowPend, r) ----
        __builtin_amdgcn_s_setprio(1);
        float pA[4] = {0,0,0,0}, pB[4] = {0,0,0,0};
        #pragma unroll
        for (int kk = 0; kk < 16; ++kk) {
            int srcl = (grp << 2) + (kk >> 2);
            float zkA = __shfl(zP[kk & 3], srcl);
            float zkB = __shfl(zc[kk & 3], srcl);
            ushort4 wvv = *(const ushort4*)&Wb1[(((grp << 4) + kk) << 6) + (q << 2)];
            float w0 = bf2f(wvv.x), w1 = bf2f(wvv.y), w2 = bf2f(wvv.z), w3 = bf2f(wvv.w);
            pA[0] = fmaf(zkA, w0, pA[0]); pA[1] = fmaf(zkA, w1, pA[1]);
            pA[2] = fmaf(zkA, w2, pA[2]); pA[3] = fmaf(zkA, w3, pA[3]);
            pB[0] = fmaf(zkB, w0, pB[0]); pB[1] = fmaf(zkB, w1, pB[1]);
            pB[2] = fmaf(zkB, w2, pB[2]); pB[3] = fmaf(zkB, w3, pB[3]);
        }
        float y1A[4], y1B[4];
        #pragma unroll
        for (int c = 0; c < 4; ++c) {
            float sA = pA[c];
            sA += __shfl_xor(sA, 16); sA += __shfl_xor(sA, 32);
            y1A[c] = fmaxf(sA + blv1[c], 0.f);
            float sB = pB[c];
            sB += __shfl_xor(sB, 16); sB += __shfl_xor(sB, 32);
            y1B[c] = fmaxf(sB + blv1[c], 0.f);
        }
        float qA[4] = {0,0,0,0}, qB[4] = {0,0,0,0};
        #pragma unroll
        for (int kk = 0; kk < 16; ++kk) {
            int srcl = (grp << 2) + (kk >> 2);
            float ykA = __shfl(y1A[kk & 3], srcl);
            float ykB = __shfl(y1B[kk & 3], srcl);
            ushort4 wvv = *(const ushort4*)&Wb2[(((grp << 4) + kk) << 6) + (q << 2)];
            float w0 = bf2f(wvv.x), w1 = bf2f(wvv.y), w2 = bf2f(wvv.z), w3 = bf2f(wvv.w);
            qA[0] = fmaf(ykA, w0, qA[0]); qA[1] = fmaf(ykA, w1, qA[1]);
            qA[2] = fmaf(ykA, w2, qA[2]); qA[3] = fmaf(ykA, w3, qA[3]);
            qB[0] = fmaf(ykB, w0, qB[0]); qB[1] = fmaf(ykB, w1, qB[1]);
            qB[2] = fmaf(ykB, w2, qB[2]); qB[3] = fmaf(ykB, w3, qB[3]);
        }
        __builtin_amdgcn_s_setprio(0);
        float y2A[4], y2B[4];
        #pragma unroll
        for (int c = 0; c < 4; ++c) {
            float sA = qA[c];
            sA += __shfl_xor(sA, 16); sA += __shfl_xor(sA, 32);
            y2A[c] = fmaxf(sA + blv2[c], 0.f);
            float sB = qB[c];
            sB += __shfl_xor(sB, 16); sB += __shfl_xor(sB, 32);
            y2B[c] = fmaxf(sB + blv2[c], 0.f);
        }
        if (grp == 0) {
            ushort4 o;
            o.x = f2bf(y2A[0]); o.y = f2bf(y2A[1]);
            o.z = f2bf(y2A[2]); o.w = f2bf(y2A[3]);
            o4[(size_t)(r0 + rowPend) * 16 + q] = o;
            ushort4 o2;
            o2.x = f2bf(y2B[0]); o2.y = f2bf(y2B[1]);
            o2.z = f2bf(y2B[2]); o2.w = f2bf(y2B[3]);
            o4[(size_t)(r0 + r) * 16 + q] = o2;
        }
        pool(__shfl(bval, rowPend), y2A);
        pool(__shfl(bval, r), y2B);
    };

    // ---- 3-slot pipeline ----
    int nIss = 0, nCon = 0;
    unsigned pv0 = 0, pv1 = 0, pv2 = 0;
    int row0 = 0, row1 = 0, row2 = 0, eb0 = 0, eb1 = 0, eb2 = 0;
    if (nIss < nTot) { pv0 = load_pv(ii, ci); row0 = ii; eb0 = ci << 5;
                       issue(pv0, &stage[wid][0][0]); adv(); ++nIss; }
    if (nIss < nTot) { pv1 = load_pv(ii, ci); row1 = ii; eb1 = ci << 5;
                       issue(pv1, &stage[wid][1][0]); adv(); ++nIss; }
    if (nIss < nTot) { pv2 = load_pv(ii, ci); row2 = ii; eb2 = ci << 5;
                       issue(pv2, &stage[wid][2][0]); adv(); ++nIss; }

    int rowCur = 0;
    float agg[4] = {0.f, 0.f, 0.f, 0.f};

#define STEP(PV, ROW, EB, SLOT)                                              \
    if (nCon < nTot) {                                                       \
        int after_ = nIss - nCon - 1;                                        \
        if (after_ >= 2)      asm volatile("s_waitcnt vmcnt(8)" ::: "memory"); \
        else if (after_ == 1) asm volatile("s_waitcnt vmcnt(4)" ::: "memory"); \
        else                  asm volatile("s_waitcnt vmcnt(0)" ::: "memory"); \
        while (rowCur < ROW) {                                               \
            finish_row(rowCur, agg);                                         \
            ++rowCur;                                                        \
            agg[0] = agg[1] = agg[2] = agg[3] = 0.f;                         \
        }                                                                    \
        accumulate(PV, &stage[wid][SLOT][0], EB, __shfl(cvl, ROW), agg);     \
        ++nCon;                                                              \
        if (nIss < nTot) {                                                   \
            PV = load_pv(ii, ci); ROW = ii; EB = ci << 5;                    \
            issue(PV, &stage[wid][SLOT][0]); adv(); ++nIss;                  \
        }                                                                    \
    }

    while (nCon < nTot) {
        STEP(pv0, row0, eb0, 0)
        STEP(pv1, row1, eb1, 1)
        STEP(pv2, row2, eb2, 2)
    }
#undef STEP

    asm volatile("s_waitcnt vmcnt(0)" ::: "memory");  // self rows (deg-0 corner)
    while (rowCur < RPW) {
        finish_row(rowCur, agg);
        ++rowCur;
        agg[0] = agg[1] = agg[2] = agg[3] = 0.f;
    }
    flush_pool();
}

// ---------------- MLP head ---------------------------------------------------
__global__ __launch_bounds__(256) void mlp_kernel(
    const float* __restrict__ pooled,  // [5][G][D]
    const float* __restrict__ l1W, const float* __restrict__ l1b,
    const float* __restrict__ l2W, const float* __restrict__ l2b,
    float* __restrict__ out) {
    __shared__ float gl[5 * D];
    __shared__ float tl[4 * D];
    int gid = blockIdx.x;
    int tid = threadIdx.x;
    for (int idx = tid; idx < 5 * D; idx += 256) {
        int k = idx >> 6;
        int d = idx & 63;
        gl[idx] = pooled[k * (G_GRAPHS * D) + gid * D + d];
    }
    __syncthreads();
    {
        float acc = l1b[tid];
        for (int m = 0; m < 5 * D; ++m)
            acc = fmaf(gl[m], l1W[m * 256 + tid], acc);
        tl[tid] = fmaxf(acc, 0.0f);
    }
    __syncthreads();
    if (tid < 5) {
        float acc = l2b[tid];
        for (int m = 0; m < 4 * D; ++m)
            acc = fmaf(tl[m], l2W[m * 5 + tid], acc);
        out[gid * 5 + tid] = acc;
    }
}

extern "C" void kernel_launch(void* const* d_in, const int* in_sizes, int n_in,
                              void* d_out, int out_size, void* d_ws, size_t ws_size,
                              hipStream_t stream) {
    const float* x     = (const float*)d_in[0];
    const int*   ei    = (const int*)d_in[1];
    const float* ea    = (const float*)d_in[2];
    const int*   batch = (const int*)d_in[3];
    const float* eps   = (const float*)d_in[4];
    const float* edgeW = (const float*)d_in[5];
    const float* edgeB = (const float*)d_in[6];
    const float* W1    = (const float*)d_in[7];
    const float* b1    = (const float*)d_in[8];
    const float* bng   = (const float*)d_in[9];
    const float* bnb   = (const float*)d_in[10];
    const float* W2    = (const float*)d_in[11];
    const float* b2    = (const float*)d_in[12];
    const float* l1W   = (const float*)d_in[13];
    const float* l1b   = (const float*)d_in[14];
    const float* l2W   = (const float*)d_in[15];
    const float* l2b   = (const float*)d_in[16];
    float* out = (float*)d_out;

    char* ws = (char*)d_ws;
    size_t nbf = (size_t)N_NODES * D * sizeof(ushort);  // 12.8 MB
    size_t off = 0;
    ushort* hbfA  = (ushort*)(ws + off); off += nbf;
    ushort* hbfB  = (ushort*)(ws + off); off += nbf;
    float* pooled = (float*)(ws + off);  off += (size_t)L_LAYERS * G_GRAPHS * D * sizeof(float);
    off = (off + 15) & ~(size_t)15;
    unsigned* perm = (unsigned*)(ws + off); off += (size_t)N_EDGES * sizeof(unsigned); // 12.8 MB
    int* deg      = (int*)(ws + off);    off += (size_t)N_NODES * sizeof(int);
    int* row_ptr  = (int*)(ws + off);    off += (size_t)(N_NODES + 1) * sizeof(int);
    int* cursor   = (int*)(ws + off);    off += (size_t)N_NODES * sizeof(int);

    hipMemsetAsync(deg, 0, (size_t)N_NODES * sizeof(int), stream);
    hipMemsetAsync(pooled, 0, (size_t)L_LAYERS * G_GRAPHS * D * sizeof(float), stream);

    xcvt_kernel<<<1024, 256, 0, stream>>>(x, hbfA);
    hist_kernel<<<2048, 256, 0, stream>>>(ei, deg);
    scan_kernel<<<1, 1024, 0, stream>>>(deg, row_ptr, cursor);
    scatter_kernel<<<2048, 256, 0, stream>>>(ei, ea, cursor, perm);

    const int waves  = (N_NODES + RPW - 1) / RPW;   // 12500
    const int blocks = (waves + 3) / 4;             // 3125

    const ushort* hcur = hbfA;
    for (int i = 0; i < L_LAYERS; ++i) {
        ushort* hnext = (i & 1) ? hbfA : hbfB;
        layer_kernel<<<blocks, 256, 0, stream>>>(
            hcur, row_ptr, perm, eps, i,
            edgeW + i * D, edgeB + i * D,
            W1 + i * D * D, b1 + i * D,
            bng + i * D, bnb + i * D,
            W2 + i * D * D, b2 + i * D,
            batch, hnext, pooled + i * G_GRAPHS * D);
        hcur = hnext;
    }
    mlp_kernel<<<G_GRAPHS, 256, 0, stream>>>(pooled, l1W, l1b, l2W, l2b, out);
}

// Round 9
// 1375.194 us; speedup vs baseline: 1.3894x; 1.3894x over previous
//
#include <hip/hip_runtime.h>

#define N_NODES 100000
#define N_EDGES 3200000
#define D 64
#define G_GRAPHS 64
#define L_LAYERS 5
#define BN_EPS 1e-5f
#define RPW 8
#define SCAN_CH 391   // 256 blocks x 391 >= 100000

typedef __fp16 h2 __attribute__((ext_vector_type(2)));
union h2u { unsigned u; h2 h; };

__device__ __forceinline__ unsigned pkf16(float a, float b) {
    h2u x; x.h = __builtin_amdgcn_cvt_pkrtz(a, b); return x.u;
}
__device__ __forceinline__ float dot2(unsigned a, unsigned b, float c) {
    h2u x, y; x.u = a; y.u = b;
    return __builtin_amdgcn_fdot2(x.h, y.h, c, false);
}

__device__ __forceinline__ unsigned short f2bf(float f) {  // RNE f32->bf16
    unsigned int u = __float_as_uint(f);
    u += 0x7FFFu + ((u >> 16) & 1u);
    return (unsigned short)(u >> 16);
}
__device__ __forceinline__ float bf2f(unsigned short v) {
    return __uint_as_float((unsigned int)v << 16);
}

// async global->LDS, 16B per lane; LDS dest is wave-uniform base + lane*16
__device__ __forceinline__ void gload_lds16(const void* g, void* l) {
    __builtin_amdgcn_global_load_lds(
        (const __attribute__((address_space(1))) unsigned int*)g,
        (__attribute__((address_space(3))) unsigned int*)l, 16, 0, 0);
}

// ---------------- x -> bf16 -------------------------------------------------
__global__ __launch_bounds__(256) void xcvt_kernel(const float* __restrict__ x,
                                                   ushort* __restrict__ xbf) {
    const float4* x4 = (const float4*)x;
    ushort4* o4 = (ushort4*)xbf;
    const int total = N_NODES * D / 4;
    for (int i = blockIdx.x * blockDim.x + threadIdx.x; i < total;
         i += gridDim.x * blockDim.x) {
        float4 v = x4[i];
        ushort4 o;
        o.x = f2bf(v.x); o.y = f2bf(v.y); o.z = f2bf(v.z); o.w = f2bf(v.w);
        o4[i] = o;
    }
}

// ---------------- dense CSR build: hist -> parallel scan -> scatter ----------
__global__ __launch_bounds__(256) void hist_kernel(const int* __restrict__ ei,
                                                   int* __restrict__ deg) {
    const int4* d4 = (const int4*)(ei + N_EDGES);
    const int n4 = N_EDGES / 4;
    for (int i = blockIdx.x * blockDim.x + threadIdx.x; i < n4;
         i += gridDim.x * blockDim.x) {
        int4 v = d4[i];
        atomicAdd(&deg[v.x], 1);
        atomicAdd(&deg[v.y], 1);
        atomicAdd(&deg[v.z], 1);
        atomicAdd(&deg[v.w], 1);
    }
}

__global__ __launch_bounds__(256) void scan_partial(const int* __restrict__ deg,
                                                    int* __restrict__ bsum) {
    __shared__ int sc[256];
    int b = blockIdx.x, t = threadIdx.x;
    int s = b * SCAN_CH, e = min(s + SCAN_CH, N_NODES);
    int sum = 0;
    for (int idx = s + t; idx < e; idx += 256) sum += deg[idx];
    sc[t] = sum;
    __syncthreads();
    for (int o = 128; o; o >>= 1) {
        if (t < o) sc[t] += sc[t + o];
        __syncthreads();
    }
    if (!t) bsum[b] = sc[0];
}

__global__ __launch_bounds__(256) void scan_base(const int* __restrict__ bsum,
                                                 int* __restrict__ bbase,
                                                 int* __restrict__ row_ptr) {
    __shared__ int sc[256];
    int t = threadIdx.x;
    int v = bsum[t];
    sc[t] = v;
    __syncthreads();
    for (int o = 1; o < 256; o <<= 1) {
        int x = (t >= o) ? sc[t - o] : 0;
        __syncthreads();
        sc[t] += x;
        __syncthreads();
    }
    bbase[t] = sc[t] - v;
    if (t == 255) row_ptr[N_NODES] = N_EDGES;
}

__global__ __launch_bounds__(256) void scan_apply(const int* __restrict__ deg,
                                                  const int* __restrict__ bbase,
                                                  int* __restrict__ row_ptr,
                                                  int* __restrict__ cursor) {
    __shared__ int sc[256];
    int b = blockIdx.x, t = threadIdx.x;
    int s = b * SCAN_CH, e = min(s + SCAN_CH, N_NODES);
    int base = bbase[b];
    for (int t0 = s; t0 < e; t0 += 256) {
        int idx = t0 + t;
        int v = (idx < e) ? deg[idx] : 0;
        sc[t] = v;
        __syncthreads();
        for (int o = 1; o < 256; o <<= 1) {
            int x = (t >= o) ? sc[t - o] : 0;
            __syncthreads();
            sc[t] += x;
            __syncthreads();
        }
        if (idx < e) {
            int ex = base + sc[t] - v;
            row_ptr[idx] = ex;
            cursor[idx] = ex;
        }
        base += sc[255];
        __syncthreads();
    }
}

// entry = (src << 15) | quant15(attr)
__device__ __forceinline__ unsigned enc_edge(int s, float a) {
    float q = fminf(fmaxf((a + 8.0f) * 2048.0f, 0.0f), 32767.0f);
    return ((unsigned)s << 15) | (unsigned)__float2int_rn(q);
}

__global__ __launch_bounds__(256) void scatter_kernel(const int* __restrict__ ei,
                                                      const float* __restrict__ ea,
                                                      int* __restrict__ cursor,
                                                      unsigned* __restrict__ perm) {
    const int4* s4 = (const int4*)ei;
    const int4* d4 = (const int4*)(ei + N_EDGES);
    const float4* a4 = (const float4*)ea;
    const int n4 = N_EDGES / 4;
    for (int i = blockIdx.x * blockDim.x + threadIdx.x; i < n4;
         i += gridDim.x * blockDim.x) {
        int4 sv = s4[i];
        int4 dv = d4[i];
        float4 av = a4[i];
        int p;
        p = atomicAdd(&cursor[dv.x], 1); perm[p] = enc_edge(sv.x, av.x);
        p = atomicAdd(&cursor[dv.y], 1); perm[p] = enc_edge(sv.y, av.y);
        p = atomicAdd(&cursor[dv.z], 1); perm[p] = enc_edge(sv.z, av.z);
        p = atomicAdd(&cursor[dv.w], 1); perm[p] = enc_edge(sv.w, av.w);
    }
}

// ---------------- fused GINE layer (R6 skeleton + f16-dot2 GEMMs) ------------
// Per wave: rows r0..r0+7 (dense CSR). 32-edge chunks staged into a 2-slot LDS
// ring via global_load_lds; vmcnt(4) keeps the next chunk in flight while the
// current accumulates and row pairs finalize (dot2 GEMMs, f16-packed weights).
__global__ __launch_bounds__(256, 3) void layer_kernel(
    const ushort* __restrict__ hbf,      // [N][D] bf16
    const int* __restrict__ row_ptr,
    const unsigned* __restrict__ perm,
    const float* __restrict__ eps, int layer,
    const float* __restrict__ edgeW, const float* __restrict__ edgeB,
    const float* __restrict__ W1, const float* __restrict__ b1,
    const float* __restrict__ bng, const float* __restrict__ bnb,
    const float* __restrict__ W2, const float* __restrict__ b2,
    const int* __restrict__ batch,
    ushort* __restrict__ hout,           // [N][D] bf16
    float* __restrict__ pooled /* [G][D] this layer */) {
    __shared__ unsigned Wp1[32 * 64];                   // 8 KB f16x2 pairs
    __shared__ unsigned Wp2[32 * 64];                   // 8 KB
    __shared__ float bl1s[D];
    __shared__ float bl2s[D];
    __shared__ __align__(16) ushort stage[4][2][2048];  // 4 waves x 2 bufs x 4KB

    const float inv_std = rsqrtf(1.0f + BN_EPS);
    const int tid = threadIdx.x;
    // pack W[2kp][c], W[2kp+1][c] into one f16x2 (bn scale folded for W1)
    for (int idx = tid; idx < 32 * 64; idx += 256) {
        int kp = idx >> 6, c = idx & 63;
        float s = bng[c] * inv_std;
        Wp1[idx] = pkf16(W1[(2 * kp) * 64 + c] * s, W1[(2 * kp + 1) * 64 + c] * s);
        Wp2[idx] = pkf16(W2[(2 * kp) * 64 + c], W2[(2 * kp + 1) * 64 + c]);
    }
    if (tid < D) {
        bl1s[tid] = fmaf(b1[tid], bng[tid] * inv_std, bnb[tid]);
        bl2s[tid] = b2[tid];
    }
    __syncthreads();

    const int lane = tid & 63;
    const int q = lane & 15;
    const int grp = lane >> 4;
    const int wid = tid >> 6;
    const int wv = blockIdx.x * 4 + wid;
    const int r0 = wv * RPW;          // N = 12500*8 exactly
    if (r0 >= N_NODES) return;

    int rpv = 0;
    if (lane < 9) rpv = row_ptr[r0 + lane];
    int cval = __shfl(rpv, lane + 1) - rpv;    // degree, valid lane<8
    int bval = 0;
    if (lane < RPW) bval = batch[r0 + lane];

    const float ev = 1.0f + eps[layer];
    const float QDEC = 4.8828125e-4f;  // 1/2048
    float w4[4], b4[4], blv1[4], blv2[4];
    {
        float4 t = ((const float4*)edgeW)[q];
        w4[0] = t.x; w4[1] = t.y; w4[2] = t.z; w4[3] = t.w;
        float4 u = ((const float4*)edgeB)[q];
        b4[0] = u.x; b4[1] = u.y; b4[2] = u.z; b4[3] = u.w;
        float4 v = ((const float4*)bl1s)[q];
        blv1[0] = v.x; blv1[1] = v.y; blv1[2] = v.z; blv1[3] = v.w;
        float4 w = ((const float4*)bl2s)[q];
        blv2[0] = w.x; blv2[1] = w.y; blv2[2] = w.z; blv2[3] = w.w;
    }
    const ushort4* h4 = (const ushort4*)hbf;
    ushort4* o4 = (ushort4*)hout;

    auto nchunks = [&](int i) { return (__shfl(cval, i) + 31) >> 5; };
    int i_iss = 0, c_iss = 0;
    while (i_iss < RPW && nchunks(i_iss) == 0) ++i_iss;
    auto advance = [&]() {
        ++c_iss;
        while (i_iss < RPW) {
            if (c_iss < nchunks(i_iss)) break;
            ++i_iss; c_iss = 0;
        }
    };
    auto load_pv = [&](int i, int c) -> unsigned {
        int base = __shfl(rpv, i);
        int rem = __shfl(cval, i) - (c << 5);
        unsigned v = 0;
        if (lane < 32 && lane < rem)
            v = __builtin_nontemporal_load(perm + base + (c << 5) + lane);
        return v;
    };
    auto issue = [&](unsigned pv, int bufId) {
        ushort* sb = &stage[wid][bufId][0];
        int eloc = lane >> 3;   // edge within group of 8
        int sub = lane & 7;     // 16B chunk within row
        #pragma unroll
        for (int j = 0; j < 4; ++j) {
            unsigned pe = __shfl(pv, (j << 3) + eloc);
            gload_lds16(hbf + (size_t)(pe >> 15) * D + sub * 8, sb + j * 512);
        }
    };
    auto accumulate = [&](unsigned pv, int bufId, int ebase, int cr, float* agg) {
        const ushort* sb = &stage[wid][bufId][0];
        #pragma unroll
        for (int k = 0; k < 8; ++k) {
            int eidx = (k << 2) | grp;
            unsigned pe = __shfl(pv, eidx);
            float m = (ebase + eidx < cr) ? 1.0f : 0.0f;
            float a = fmaf((float)(pe & 0x7FFFu), QDEC, -8.0f);
            ushort4 hv = *(const ushort4*)(sb + (eidx << 6) + (q << 2));
            agg[0] = fmaf(m, fmaxf(fmaf(a, w4[0], b4[0]) + bf2f(hv.x), 0.f), agg[0]);
            agg[1] = fmaf(m, fmaxf(fmaf(a, w4[1], b4[1]) + bf2f(hv.y), 0.f), agg[1]);
            agg[2] = fmaf(m, fmaxf(fmaf(a, w4[2], b4[2]) + bf2f(hv.z), 0.f), agg[2]);
            agg[3] = fmaf(m, fmaxf(fmaf(a, w4[3], b4[3]) + bf2f(hv.w), 0.f), agg[3]);
        }
    };

    // ---- pipeline prologue: one chunk in flight ----
    bool haveNext = (i_iss < RPW);
    unsigned pvNext = haveNext ? load_pv(i_iss, c_iss) : 0u;
    unsigned pvFlight = 0;
    int bufFlight = 0, bufNext = 0;
    if (haveNext) {
        issue(pvNext, 0);
        pvFlight = pvNext;
        bufFlight = 0;
        advance();
        haveNext = (i_iss < RPW);
        pvNext = haveNext ? load_pv(i_iss, c_iss) : 0u;
        bufNext = 1;
    }

    int cur_g = -1;
    float rm[4] = {0.f, 0.f, 0.f, 0.f};
    auto flush_pool = [&]() {
        if (cur_g >= 0 && grp == 0) {
            unsigned* p = (unsigned*)&pooled[cur_g * D + 4 * q];
            atomicMax(p + 0, __float_as_uint(rm[0]));
            atomicMax(p + 1, __float_as_uint(rm[1]));
            atomicMax(p + 2, __float_as_uint(rm[2]));
            atomicMax(p + 3, __float_as_uint(rm[3]));
        }
    };
    auto pool = [&](int bg, const float* y) {
        if (bg != cur_g) {
            flush_pool();
            cur_g = bg;
            rm[0] = y[0]; rm[1] = y[1]; rm[2] = y[2]; rm[3] = y[3];
        } else {
            rm[0] = fmaxf(rm[0], y[0]); rm[1] = fmaxf(rm[1], y[1]);
            rm[2] = fmaxf(rm[2], y[2]); rm[3] = fmaxf(rm[3], y[3]);
        }
    };

    unsigned zpP0 = 0, zpP1 = 0;   // pending row's packed z

    for (int ai = 0; ai < RPW; ++ai) {
        int crA = __shfl(cval, ai);
        int nchA = (crA + 31) >> 5;
        ushort4 hs4 = h4[(size_t)(r0 + ai) * 16 + q];   // self row (prefetch)
        float agg[4] = {0.f, 0.f, 0.f, 0.f};
        for (int ac = 0; ac < nchA; ++ac) {
            unsigned pvAcc = pvFlight;
            int bufAcc = bufFlight;
            if (haveNext) {
                issue(pvNext, bufNext);
                pvFlight = pvNext;
                bufFlight = bufNext;
                advance();
                haveNext = (i_iss < RPW);
                pvNext = haveNext ? load_pv(i_iss, c_iss) : 0u;
                bufNext ^= 1;
                asm volatile("s_waitcnt vmcnt(4)" ::: "memory");
            } else {
                asm volatile("s_waitcnt vmcnt(0)" ::: "memory");
            }
            accumulate(pvAcc, bufAcc, ac << 5, crA, agg);
        }
        // reduce the 4 grp replicas
        #pragma unroll
        for (int c = 0; c < 4; ++c) {
            agg[c] += __shfl_xor(agg[c], 16);
            agg[c] += __shfl_xor(agg[c], 32);
        }
        float z0 = fmaf(ev, bf2f(hs4.x), agg[0]);
        float z1 = fmaf(ev, bf2f(hs4.y), agg[1]);
        float z2 = fmaf(ev, bf2f(hs4.z), agg[2]);
        float z3 = fmaf(ev, bf2f(hs4.w), agg[3]);
        unsigned zc0 = pkf16(z0, z1), zc1 = pkf16(z2, z3);
        if (!(ai & 1)) {
            zpP0 = zc0; zpP1 = zc1;
            continue;
        }
        // ---- finalize row pair (r0+ai-1, r0+ai): dot2 GEMMs ----
        float pA[4] = {0,0,0,0}, pB[4] = {0,0,0,0};
        #pragma unroll
        for (int kk2 = 0; kk2 < 8; ++kk2) {
            int kp = (grp << 3) + kk2;           // k-pair index this grp covers
            int srcl = (grp << 2) + (kk2 >> 1);  // lane holding zpair[kp]
            unsigned zA = __shfl((kk2 & 1) ? zpP1 : zpP0, srcl);
            unsigned zB = __shfl((kk2 & 1) ? zc1 : zc0, srcl);
            uint4 wq = *(const uint4*)&Wp1[(kp << 6) + (q << 2)];
            pA[0] = dot2(zA, wq.x, pA[0]); pA[1] = dot2(zA, wq.y, pA[1]);
            pA[2] = dot2(zA, wq.z, pA[2]); pA[3] = dot2(zA, wq.w, pA[3]);
            pB[0] = dot2(zB, wq.x, pB[0]); pB[1] = dot2(zB, wq.y, pB[1]);
            pB[2] = dot2(zB, wq.z, pB[2]); pB[3] = dot2(zB, wq.w, pB[3]);
        }
        float y1A[4], y1B[4];
        #pragma unroll
        for (int c = 0; c < 4; ++c) {
            float sA = pA[c];
            sA += __shfl_xor(sA, 16); sA += __shfl_xor(sA, 32);
            y1A[c] = fmaxf(sA + blv1[c], 0.f);
            float sB = pB[c];
            sB += __shfl_xor(sB, 16); sB += __shfl_xor(sB, 32);
            y1B[c] = fmaxf(sB + blv1[c], 0.f);
        }
        unsigned yA0 = pkf16(y1A[0], y1A[1]), yA1 = pkf16(y1A[2], y1A[3]);
        unsigned yB0 = pkf16(y1B[0], y1B[1]), yB1 = pkf16(y1B[2], y1B[3]);
        float qA[4] = {0,0,0,0}, qB[4] = {0,0,0,0};
        #pragma unroll
        for (int kk2 = 0; kk2 < 8; ++kk2) {
            int kp = (grp << 3) + kk2;
            int srcl = (grp << 2) + (kk2 >> 1);
            unsigned zA = __shfl((kk2 & 1) ? yA1 : yA0, srcl);
            unsigned zB = __shfl((kk2 & 1) ? yB1 : yB0, srcl);
            uint4 wq = *(const uint4*)&Wp2[(kp << 6) + (q << 2)];
            qA[0] = dot2(zA, wq.x, qA[0]); qA[1] = dot2(zA, wq.y, qA[1]);
            qA[2] = dot2(zA, wq.z, qA[2]); qA[3] = dot2(zA, wq.w, qA[3]);
            qB[0] = dot2(zB, wq.x, qB[0]); qB[1] = dot2(zB, wq.y, qB[1]);
            qB[2] = dot2(zB, wq.z, qB[2]); qB[3] = dot2(zB, wq.w, qB[3]);
        }
        float y2A[4], y2B[4];
        #pragma unroll
        for (int c = 0; c < 4; ++c) {
            float sA = qA[c];
            sA += __shfl_xor(sA, 16); sA += __shfl_xor(sA, 32);
            y2A[c] = fmaxf(sA + blv2[c], 0.f);
            float sB = qB[c];
            sB += __shfl_xor(sB, 16); sB += __shfl_xor(sB, 32);
            y2B[c] = fmaxf(sB + blv2[c], 0.f);
        }
        if (grp == 0) {
            ushort4 o;
            o.x = f2bf(y2A[0]); o.y = f2bf(y2A[1]);
            o.z = f2bf(y2A[2]); o.w = f2bf(y2A[3]);
            o4[(size_t)(r0 + ai - 1) * 16 + q] = o;
            ushort4 o2;
            o2.x = f2bf(y2B[0]); o2.y = f2bf(y2B[1]);
            o2.z = f2bf(y2B[2]); o2.w = f2bf(y2B[3]);
            o4[(size_t)(r0 + ai) * 16 + q] = o2;
        }
        pool(__shfl(bval, ai - 1), y2A);
        pool(__shfl(bval, ai), y2B);
    }
    flush_pool();
}

// ---------------- MLP head ---------------------------------------------------
__global__ __launch_bounds__(256) void mlp_kernel(
    const float* __restrict__ pooled,  // [5][G][D]
    const float* __restrict__ l1W, const float* __restrict__ l1b,
    const float* __restrict__ l2W, const float* __restrict__ l2b,
    float* __restrict__ out) {
    __shared__ float gl[5 * D];
    __shared__ float tl[4 * D];
    int gid = blockIdx.x;
    int tid = threadIdx.x;
    for (int idx = tid; idx < 5 * D; idx += 256) {
        int k = idx >> 6;
        int d = idx & 63;
        gl[idx] = pooled[k * (G_GRAPHS * D) + gid * D + d];
    }
    __syncthreads();
    {
        float acc = l1b[tid];
        for (int m = 0; m < 5 * D; ++m)
            acc = fmaf(gl[m], l1W[m * 256 + tid], acc);
        tl[tid] = fmaxf(acc, 0.0f);
    }
    __syncthreads();
    if (tid < 5) {
        float acc = l2b[tid];
        for (int m = 0; m < 4 * D; ++m)
            acc = fmaf(tl[m], l2W[m * 5 + tid], acc);
        out[gid * 5 + tid] = acc;
    }
}

extern "C" void kernel_launch(void* const* d_in, const int* in_sizes, int n_in,
                              void* d_out, int out_size, void* d_ws, size_t ws_size,
                              hipStream_t stream) {
    const float* x     = (const float*)d_in[0];
    const int*   ei    = (const int*)d_in[1];
    const float* ea    = (const float*)d_in[2];
    const int*   batch = (const int*)d_in[3];
    const float* eps   = (const float*)d_in[4];
    const float* edgeW = (const float*)d_in[5];
    const float* edgeB = (const float*)d_in[6];
    const float* W1    = (const float*)d_in[7];
    const float* b1    = (const float*)d_in[8];
    const float* bng   = (const float*)d_in[9];
    const float* bnb   = (const float*)d_in[10];
    const float* W2    = (const float*)d_in[11];
    const float* b2    = (const float*)d_in[12];
    const float* l1W   = (const float*)d_in[13];
    const float* l1b   = (const float*)d_in[14];
    const float* l2W   = (const float*)d_in[15];
    const float* l2b   = (const float*)d_in[16];
    float* out = (float*)d_out;

    char* ws = (char*)d_ws;
    size_t nbf = (size_t)N_NODES * D * sizeof(ushort);  // 12.8 MB
    size_t off = 0;
    ushort* hbfA  = (ushort*)(ws + off); off += nbf;
    ushort* hbfB  = (ushort*)(ws + off); off += nbf;
    float* pooled = (float*)(ws + off);  off += (size_t)L_LAYERS * G_GRAPHS * D * sizeof(float);
    off = (off + 15) & ~(size_t)15;
    unsigned* perm = (unsigned*)(ws + off); off += (size_t)N_EDGES * sizeof(unsigned); // 12.8 MB
    int* deg      = (int*)(ws + off);    off += (size_t)N_NODES * sizeof(int);
    int* row_ptr  = (int*)(ws + off);    off += (size_t)(N_NODES + 1) * sizeof(int);
    int* cursor   = (int*)(ws + off);    off += (size_t)N_NODES * sizeof(int);
    int* bsum     = (int*)(ws + off);    off += 256 * sizeof(int);
    int* bbase    = (int*)(ws + off);    off += 256 * sizeof(int);

    hipMemsetAsync(deg, 0, (size_t)N_NODES * sizeof(int), stream);
    hipMemsetAsync(pooled, 0, (size_t)L_LAYERS * G_GRAPHS * D * sizeof(float), stream);

    xcvt_kernel<<<1024, 256, 0, stream>>>(x, hbfA);
    hist_kernel<<<2048, 256, 0, stream>>>(ei, deg);
    scan_partial<<<256, 256, 0, stream>>>(deg, bsum);
    scan_base<<<1, 256, 0, stream>>>(bsum, bbase, row_ptr);
    scan_apply<<<256, 256, 0, stream>>>(deg, bbase, row_ptr, cursor);
    scatter_kernel<<<2048, 256, 0, stream>>>(ei, ea, cursor, perm);

    const int waves  = (N_NODES + RPW - 1) / RPW;   // 12500
    const int blocks = (waves + 3) / 4;             // 3125

    const ushort* hcur = hbfA;
    for (int i = 0; i < L_LAYERS; ++i) {
        ushort* hnext = (i & 1) ? hbfA : hbfB;
        layer_kernel<<<blocks, 256, 0, stream>>>(
            hcur, row_ptr, perm, eps, i,
            edgeW + i * D, edgeB + i * D,
            W1 + i * D * D, b1 + i * D,
            bng + i * D, bnb + i * D,
            W2 + i * D * D, b2 + i * D,
            batch, hnext, pooled + i * G_GRAPHS * D);
        hcur = hnext;
    }
    mlp_kernel<<<G_GRAPHS, 256, 0, stream>>>(pooled, l1W, l1b, l2W, l2b, out);
}